// Round 3
// baseline (532.981 us; speedup 1.0000x reference)
//
#include <hip/hip_runtime.h>

#define HW 16384
#define Nn 4096

typedef __bf16 bf16x8 __attribute__((ext_vector_type(8)));
typedef unsigned short us8t __attribute__((ext_vector_type(8)));
typedef float f32x4 __attribute__((ext_vector_type(4)));
typedef float f32x16 __attribute__((ext_vector_type(16)));

__device__ __forceinline__ unsigned short f2bf(float f) {
    unsigned int u = __float_as_uint(f);
    u = (u + 0x7fffu + ((u >> 16) & 1u)) >> 16;  // RNE
    return (unsigned short)u;
}
__device__ __forceinline__ float bf2f(unsigned int h) {
    return __uint_as_float(h << 16);
}
__device__ __forceinline__ f32x4 mfma16(us8t a, us8t b, f32x4 c) {
    return __builtin_amdgcn_mfma_f32_16x16x32_bf16(
        __builtin_bit_cast(bf16x8, a), __builtin_bit_cast(bf16x8, b), c, 0, 0, 0);
}
__device__ __forceinline__ f32x16 mfma32(us8t a, us8t b, f32x16 c) {
    return __builtin_amdgcn_mfma_f32_32x32x16_bf16(
        __builtin_bit_cast(bf16x8, a), __builtin_bit_cast(bf16x8, b), c, 0, 0, 0);
}

// async global->LDS, 16B per lane (wave writes base + lane*16)
__device__ __forceinline__ void gload16(const float* g, float* l) {
    __builtin_amdgcn_global_load_lds(
        (const __attribute__((address_space(1))) unsigned int*)g,
        (__attribute__((address_space(3))) unsigned int*)l, 16, 0, 0);
}

// ---------------- K0: weights -> bf16, transposed [d][c] ----------------
__global__ __launch_bounds__(256) void k_wt(const float* __restrict__ W1,
                                            const float* __restrict__ W2,
                                            const float* __restrict__ Wp,
                                            unsigned short* __restrict__ WT) {
    const int m = blockIdx.x >> 8;     // matrix 0..2
    const int d = blockIdx.x & 255;
    const int c = threadIdx.x;
    const float* W = (m == 0) ? W1 : (m == 1) ? W2 : Wp;
    WT[m * 65536 + d * 256 + c] = f2bf(W[c * 256 + d]);
}

// ---------------- K1: S[b,p,d] = sum_c f[b,c,p] * W1[c,d]  (bf16 out) ----------------
// v4: the v2/v3 convoy fix. v3 had 1 block/CU (128 KiB LDS, 512 thr) with a vmcnt(0)
// barrier drain every k-iter -> every wave on the CU parked, per-CU BW ~6 GB/s, chip
// pinned at 1.6 TB/s regardless of access pattern. v4 restores inter-block TLP:
// 256 threads (4 waves), 32 KiB LDS (fs[2][16][256] f32, BK=16, dbuf) -> 4 blocks/CU.
// Tile 256p x 64d (wave = 64p x 64d, acc 2x2 f32x16). Staging unchanged: 1 KiB
// global_load_lds per instruction (contiguous p-row), stage-next-before-compute,
// single barrier per iter -- other resident blocks cover the drain.
__global__ __launch_bounds__(256) void k_gemm1(const float* __restrict__ f,
                                               const unsigned short* __restrict__ W1T,
                                               unsigned short* __restrict__ S, int b0) {
    __shared__ __align__(16) float fs[2][16][256];  // 32 KiB: [buf][c-local][p-local]

    int blk = blockIdx.x;
    if ((gridDim.x & 7) == 0) {              // XCD-aware chunked swizzle
        const int chunk = gridDim.x >> 3;
        blk = (blk & 7) * chunk + (blk >> 3);
    }
    const int bl = blk >> 8;                 // local batch (256 blocks per batch)
    const int b = b0 + bl;
    const int pt = (blk >> 2) & 63;          // p-tile
    const int dt = blk & 2 ? (blk & 3) : (blk & 3);  // d-tile 0..3 (fastest: shares f window)
    const int p0 = pt << 8;                  // 256-p tile
    const int d0 = (blk & 3) << 6;           // 64-d tile
    const int t = threadIdx.x;
    const int lane = t & 63;
    const int w = t >> 6;                    // wave 0..3 = p-subtile (64 rows)
    const int l5 = lane >> 5;
    const int r31 = lane & 31;
    (void)dt;

    const float* fb = f + ((size_t)b << 22) + p0;

    f32x16 acc[2][2];
#pragma unroll
    for (int i = 0; i < 2; ++i)
#pragma unroll
        for (int j = 0; j < 2; ++j)
#pragma unroll
            for (int r = 0; r < 16; ++r) acc[i][j][r] = 0.f;

    // stage k-tile kt (16 c-rows) into buffer bufi: wave w owns c-rows 4w..4w+3.
    // one global_load_lds per c-row: 64 lanes x 16B = 1 KiB contiguous (p0..p0+255).
    auto stage = [&](int bufi, int kt) {
#pragma unroll
        for (int i = 0; i < 4; ++i) {
            const int c = (w << 2) + i;
            gload16(fb + ((size_t)((kt << 4) + c) << 14) + (lane << 2), &fs[bufi][c][0]);
        }
    };

    stage(0, 0);
    __syncthreads();  // buf0 ready (vmcnt drain)

    const int plA = (w << 6) + r31;   // A p-row base (mt adds 32)
    const int cb = l5 << 3;           // k-group within K16

    for (int kt = 0; kt < 16; ++kt) {
        const int cur = kt & 1;
        if (kt < 15) stage(cur ^ 1, kt + 1);  // loads fly during compute below

        // B frags for this K16 chunk (L2/L3-resident weights)
        us8t bfr[2];
#pragma unroll
        for (int nt = 0; nt < 2; ++nt) {
            const int col = d0 + (nt << 5) + r31;
            bfr[nt] = *(const us8t*)(W1T + (col << 8) + (kt << 4) + cb);
        }

        // A frags from LDS: 8x ds_read_b32 per mt, bank = p%32 -> conflict-free
        us8t A[2];
#pragma unroll
        for (int mt = 0; mt < 2; ++mt) {
            const int pl = plA + (mt << 5);
            float av[8];
#pragma unroll
            for (int j = 0; j < 8; ++j) av[j] = fs[cur][cb + j][pl];
#pragma unroll
            for (int j = 0; j < 8; ++j) A[mt][j] = f2bf(av[j]);
        }
#pragma unroll
        for (int mt = 0; mt < 2; ++mt)
#pragma unroll
            for (int nt = 0; nt < 2; ++nt)
                acc[mt][nt] = mfma32(A[mt], bfr[nt], acc[mt][nt]);

        __syncthreads();  // drains stage(kt+1); other blocks on the CU cover the stall
    }

    // store S bf16: 32x32 C layout col=lane&31, row=(reg&3)+8*(reg>>2)+4*(lane>>5)
    unsigned short* Sp = S + ((((size_t)bl << 14) + p0) << 8);
    const int rbase = l5 << 2;
#pragma unroll
    for (int mt = 0; mt < 2; ++mt)
#pragma unroll
        for (int nt = 0; nt < 2; ++nt) {
            const int d = d0 + (nt << 5) + r31;
#pragma unroll
            for (int r = 0; r < 16; ++r) {
                const int row = (w << 6) + (mt << 5) + ((r >> 2) << 3) + (r & 3) + rbase;
                Sp[((size_t)row << 8) + d] = f2bf(acc[mt][nt][r]);
            }
        }
}

// ---------------- K2: gather+b1+relu -> GEMM2+b2+posenc -> GEMM3+bp -> out ----------------
// block: 64 points x 256 cols, 256 threads (4 waves, n-split)
__global__ __launch_bounds__(256) void k_fused(const unsigned short* __restrict__ S,
                                               const float* __restrict__ verts,
                                               const int* __restrict__ iszp,
                                               const unsigned short* __restrict__ W2T,
                                               const unsigned short* __restrict__ WpT,
                                               const float* __restrict__ b1,
                                               const float* __restrict__ b2,
                                               const float* __restrict__ bpv,
                                               float* __restrict__ out, int b0) {
    __shared__ __align__(16) unsigned short hT[64][264];  // pitch 528B = 16*33 (odd quad)
    __shared__ __align__(16) int pIdx[64][4];
    __shared__ __align__(16) float wBl[64][4];
    __shared__ float vps[64][2];
    __shared__ __align__(16) float b1s[256];
    __shared__ float b2s[256], bps[256];

    const int blk = blockIdx.x;
    const int bl = blk >> 6;
    const int b = b0 + bl;
    const int n0 = (blk & 63) << 6;
    const int t = threadIdx.x;
    const int lane = t & 63;
    const int w = t >> 6;

    b1s[t] = b1[t];
    b2s[t] = b2[t];
    bps[t] = bpv[t];

    if (t < 64) {
        const float isz = (float)iszp[0];
        const size_t vo = ((size_t)b * Nn + n0 + t) << 1;
        const float vx = verts[vo + 0];
        const float vy = verts[vo + 1];
        const float gs = 127.0f / (isz - 1.0f);
        const float ix = fminf(fmaxf(vx * gs, 0.0f), 127.0f);
        const float iy = fminf(fmaxf(vy * gs, 0.0f), 127.0f);
        const float x0 = floorf(ix), y0 = floorf(iy);
        const float wx = ix - x0, wy = iy - y0;
        const int x0i = (int)x0, y0i = (int)y0;
        const int x1i = min(x0i + 1, 127), y1i = min(y0i + 1, 127);
        pIdx[t][0] = (y0i << 7) + x0i;
        pIdx[t][1] = (y0i << 7) + x1i;
        pIdx[t][2] = (y1i << 7) + x0i;
        pIdx[t][3] = (y1i << 7) + x1i;
        wBl[t][0] = (1.0f - wx) * (1.0f - wy);
        wBl[t][1] = wx * (1.0f - wy);
        wBl[t][2] = (1.0f - wx) * wy;
        wBl[t][3] = wx * wy;
        vps[t][0] = vx / isz;
        vps[t][1] = vy / isz;
    }
    __syncthreads();

    // ---- gather (coalesced: 512B bf16 rows) + b1 + relu -> hT ----
    {
        const unsigned short* Sb = S + ((size_t)bl << 22);
        const float4 bl1 = *(const float4*)&b1s[lane << 2];
        for (int i = 0; i < 16; ++i) {
            const int r = (w << 4) + i;
            const int4 pp = *(const int4*)pIdx[r];
            const float4 wt = *(const float4*)wBl[r];
            const uint2 a0 = *(const uint2*)(Sb + ((size_t)pp.x << 8) + (lane << 2));
            const uint2 a1 = *(const uint2*)(Sb + ((size_t)pp.y << 8) + (lane << 2));
            const uint2 a2 = *(const uint2*)(Sb + ((size_t)pp.z << 8) + (lane << 2));
            const uint2 a3 = *(const uint2*)(Sb + ((size_t)pp.w << 8) + (lane << 2));
            float d0 = wt.x * bf2f(a0.x & 0xffffu) + wt.y * bf2f(a1.x & 0xffffu) +
                       wt.z * bf2f(a2.x & 0xffffu) + wt.w * bf2f(a3.x & 0xffffu) + bl1.x;
            float d1 = wt.x * bf2f(a0.x >> 16) + wt.y * bf2f(a1.x >> 16) +
                       wt.z * bf2f(a2.x >> 16) + wt.w * bf2f(a3.x >> 16) + bl1.y;
            float d2 = wt.x * bf2f(a0.y & 0xffffu) + wt.y * bf2f(a1.y & 0xffffu) +
                       wt.z * bf2f(a2.y & 0xffffu) + wt.w * bf2f(a3.y & 0xffffu) + bl1.z;
            float d3 = wt.x * bf2f(a0.y >> 16) + wt.y * bf2f(a1.y >> 16) +
                       wt.z * bf2f(a2.y >> 16) + wt.w * bf2f(a3.y >> 16) + bl1.w;
            d0 = fmaxf(d0, 0.0f);
            d1 = fmaxf(d1, 0.0f);
            d2 = fmaxf(d2, 0.0f);
            d3 = fmaxf(d3, 0.0f);
            uint2 pk;
            pk.x = (unsigned)f2bf(d0) | ((unsigned)f2bf(d1) << 16);
            pk.y = (unsigned)f2bf(d2) | ((unsigned)f2bf(d3) << 16);
            *(uint2*)&hT[r][lane << 2] = pk;
        }
    }
    __syncthreads();

    const int mrow = lane & 15;
    const int kg = (lane >> 4) << 3;
    const int r0 = (lane >> 4) << 2;
    const int n0w = w << 6;

    // ---- GEMM2: vfeat = h @ W2 ----
    f32x4 acc[4][4];
#pragma unroll
    for (int i = 0; i < 4; ++i)
#pragma unroll
        for (int j = 0; j < 4; ++j) acc[i][j] = (f32x4){0.f, 0.f, 0.f, 0.f};

    us8t bnx[4];
#pragma unroll
    for (int nt = 0; nt < 4; ++nt)
        bnx[nt] = *(const us8t*)(W2T + ((n0w + (nt << 4) + mrow) << 8) + kg);
    for (int k0 = 0; k0 < 256; k0 += 32) {
        us8t bcur[4];
#pragma unroll
        for (int nt = 0; nt < 4; ++nt) bcur[nt] = bnx[nt];
        if (k0 < 224) {
#pragma unroll
            for (int nt = 0; nt < 4; ++nt)
                bnx[nt] = *(const us8t*)(W2T + ((n0w + (nt << 4) + mrow) << 8) + k0 + 32 + kg);
        }
        us8t af[4];
#pragma unroll
        for (int mt = 0; mt < 4; ++mt)
            af[mt] = *(const us8t*)&hT[(mt << 4) + mrow][k0 + kg];
#pragma unroll
        for (int mt = 0; mt < 4; ++mt)
#pragma unroll
            for (int nt = 0; nt < 4; ++nt)
                acc[mt][nt] = mfma16(af[mt], bcur[nt], acc[mt][nt]);
    }
    __syncthreads();  // all hT reads done before overwrite

    // ---- epilogue: g = vfeat + b2 + posenc -> hT (bf16) ----
    const float C2 = -0.20762050593046f;  // -log2(10000)/64
#pragma unroll
    for (int nt = 0; nt < 4; ++nt) {
        const int col = n0w + (nt << 4) + mrow;
        const float bias2 = b2s[col];
        const int ci = col & 127;
        const float dv = exp2f((float)(ci >> 1) * C2) * 1000.0f;
        const int sel = col >> 7;  // 0 -> x, 1 -> y
#pragma unroll
        for (int mt = 0; mt < 4; ++mt)
#pragma unroll
            for (int j = 0; j < 4; ++j) {
                const int row = (mt << 4) + r0 + j;
                const float ang = vps[row][sel] * dv;
                const float pe = (col & 1) ? __cosf(ang) : __sinf(ang);
                hT[row][col] = f2bf(acc[mt][nt][j] + bias2 + pe);
            }
    }
    __syncthreads();

    // ---- GEMM3: out = g @ Wp + bp ----
#pragma unroll
    for (int i = 0; i < 4; ++i)
#pragma unroll
        for (int j = 0; j < 4; ++j) acc[i][j] = (f32x4){0.f, 0.f, 0.f, 0.f};
#pragma unroll
    for (int nt = 0; nt < 4; ++nt)
        bnx[nt] = *(const us8t*)(WpT + ((n0w + (nt << 4) + mrow) << 8) + kg);
    for (int k0 = 0; k0 < 256; k0 += 32) {
        us8t bcur[4];
#pragma unroll
        for (int nt = 0; nt < 4; ++nt) bcur[nt] = bnx[nt];
        if (k0 < 224) {
#pragma unroll
            for (int nt = 0; nt < 4; ++nt)
                bnx[nt] = *(const us8t*)(WpT + ((n0w + (nt << 4) + mrow) << 8) + k0 + 32 + kg);
        }
        us8t af[4];
#pragma unroll
        for (int mt = 0; mt < 4; ++mt)
            af[mt] = *(const us8t*)&hT[(mt << 4) + mrow][k0 + kg];
#pragma unroll
        for (int mt = 0; mt < 4; ++mt)
#pragma unroll
            for (int nt = 0; nt < 4; ++nt)
                acc[mt][nt] = mfma16(af[mt], bcur[nt], acc[mt][nt]);
    }

    float* ob = out + (((size_t)b * Nn + n0) << 8);
#pragma unroll
    for (int nt = 0; nt < 4; ++nt) {
        const int col = n0w + (nt << 4) + mrow;
        const float bb = bps[col];
#pragma unroll
        for (int mt = 0; mt < 4; ++mt)
#pragma unroll
            for (int j = 0; j < 4; ++j) {
                const int row = (mt << 4) + r0 + j;
                ob[((size_t)row << 8) + col] = acc[mt][nt][j] + bb;
            }
    }
}

extern "C" void kernel_launch(void* const* d_in, const int* in_sizes, int n_in,
                              void* d_out, int out_size, void* d_ws, size_t ws_size,
                              hipStream_t stream) {
    const float* f = (const float*)d_in[0];
    const float* verts = (const float*)d_in[1];
    const int* isz = (const int*)d_in[2];
    const float* W1 = (const float*)d_in[3];
    const float* b1 = (const float*)d_in[4];
    const float* W2 = (const float*)d_in[5];
    const float* b2 = (const float*)d_in[6];
    const float* Wp = (const float*)d_in[7];
    const float* bp = (const float*)d_in[8];
    float* out = (float*)d_out;

    unsigned short* WT = (unsigned short*)d_ws;                       // 3 x 128KB bf16 transposed
    const size_t S_OFF = 512u << 10;
    unsigned short* S = (unsigned short*)((char*)d_ws + S_OFF);

    const size_t perBatch = (size_t)HW * 256 * 2;  // 8 MB bf16
    size_t sbytes = (ws_size > S_OFF) ? (ws_size - S_OFF) : 0;
    int nbMax = (int)(sbytes / perBatch);
    if (nbMax < 1) nbMax = 1;
    if (nbMax > 16) nbMax = 16;

    k_wt<<<dim3(768), dim3(256), 0, stream>>>(W1, W2, Wp, WT);
    for (int b0 = 0; b0 < 16; b0 += nbMax) {
        const int nb = (16 - b0 < nbMax) ? (16 - b0) : nbMax;
        k_gemm1<<<dim3(nb * 256), dim3(256), 0, stream>>>(f, WT, S, b0);
        k_fused<<<dim3(nb * 64), dim3(256), 0, stream>>>(S, verts, isz, WT + 65536, WT + 131072,
                                                         b1, b2, bp, out, b0);
    }
}

// Round 5
// 489.337 us; speedup vs baseline: 1.0892x; 1.0892x over previous
//
#include <hip/hip_runtime.h>

#define HW 16384
#define Nn 4096

typedef __bf16 bf16x8 __attribute__((ext_vector_type(8)));
typedef unsigned short us8t __attribute__((ext_vector_type(8)));
typedef float f32x4 __attribute__((ext_vector_type(4)));

__device__ __forceinline__ unsigned short f2bf(float f) {
    unsigned int u = __float_as_uint(f);
    u = (u + 0x7fffu + ((u >> 16) & 1u)) >> 16;  // RNE
    return (unsigned short)u;
}
__device__ __forceinline__ float bf2f(unsigned int h) {
    return __uint_as_float(h << 16);
}
__device__ __forceinline__ unsigned int pack2(unsigned short a, unsigned short b) {
    return (unsigned)a | ((unsigned)b << 16);
}
__device__ __forceinline__ f32x4 mfma16(us8t a, us8t b, f32x4 c) {
    return __builtin_amdgcn_mfma_f32_16x16x32_bf16(
        __builtin_bit_cast(bf16x8, a), __builtin_bit_cast(bf16x8, b), c, 0, 0, 0);
}

// ---------------- K0: weights -> bf16, transposed [d][c] ----------------
__global__ __launch_bounds__(256) void k_wt(const float* __restrict__ W1,
                                            const float* __restrict__ W2,
                                            const float* __restrict__ Wp,
                                            unsigned short* __restrict__ WT) {
    const int m = blockIdx.x >> 8;     // matrix 0..2
    const int d = blockIdx.x & 255;
    const int c = threadIdx.x;
    const float* W = (m == 0) ? W1 : (m == 1) ? W2 : Wp;
    WT[m * 65536 + d * 256 + c] = f2bf(W[c * 256 + d]);
}

// ---------------- K1: fT[b][p][c] = bf16(f[b][c][p]) -- pure streaming transpose ------
// Replaces the per-pixel GEMM1 entirely (interp and matmul commute; GEMM1 moves to
// k_fused over 4096 points instead of 16384 pixels = 4x fewer FLOPs). This kernel is
// pure copy-shaped: 16 in-flight float4 loads/thread (1KiB/row coalesced), LDS
// column-transpose (conflict-free by construction), full-line uint4 stores.
// Tile: 64 c x 256 p. 34.8 KiB LDS -> 4 blocks/CU.
__global__ __launch_bounds__(256) void k_tr(const float* __restrict__ f,
                                            unsigned short* __restrict__ fT, int b0) {
    __shared__ __align__(16) unsigned short fsh[64][272];  // pitch 544B: column reads hit 32 banks

    int blk = blockIdx.x;
    if ((gridDim.x & 7) == 0) {              // XCD-aware chunked swizzle: batch-per-XCD
        const int chunk = gridDim.x >> 3;
        blk = (blk & 7) * chunk + (blk >> 3);
    }
    const int bl = blk >> 8;                 // local batch (256 tiles per batch)
    const int b = b0 + bl;
    const int j = blk & 255;
    const int p0 = (j >> 2) << 8;            // 256-pixel window
    const int c0 = (j & 3) << 6;             // 64-channel window
    const int t = threadIdx.x;
    const int lane = t & 63;
    const int w = t >> 6;

    const float* fb = f + ((size_t)b << 22);

    // read: wave w owns c-rows w*16..w*16+15; each row = 64 lanes x 16B = 1KiB coalesced
    float4 v[16];
#pragma unroll
    for (int i = 0; i < 16; ++i) {
        const int c = c0 + (w << 4) + i;
        v[i] = *(const float4*)(fb + ((size_t)c << 14) + p0 + (lane << 2));
    }
#pragma unroll
    for (int i = 0; i < 16; ++i) {
        const int cl = (w << 4) + i;
        unsigned short* d = &fsh[cl][lane << 2];
        d[0] = f2bf(v[i].x);
        d[1] = f2bf(v[i].y);
        d[2] = f2bf(v[i].z);
        d[3] = f2bf(v[i].w);
    }
    __syncthreads();

    // write: thread t = p-row; read LDS column (2 lanes/bank = free), 8x uint4 = 128B
    unsigned short* orow = fT + ((size_t)bl << 22) + ((size_t)(p0 + t) << 8) + c0;
#pragma unroll
    for (int k = 0; k < 8; ++k) {
        uint4 q;
        q.x = pack2(fsh[(k << 3) + 0][t], fsh[(k << 3) + 1][t]);
        q.y = pack2(fsh[(k << 3) + 2][t], fsh[(k << 3) + 3][t]);
        q.z = pack2(fsh[(k << 3) + 4][t], fsh[(k << 3) + 5][t]);
        q.w = pack2(fsh[(k << 3) + 6][t], fsh[(k << 3) + 7][t]);
        *(uint4*)(orow + (k << 3)) = q;
    }
}

// ---------------- K2: gather -> GEMM1+b1+relu -> GEMM2+b2+posenc -> GEMM3+bp -> out ----
// block: 64 points x 256 cols, 256 threads (4 waves, n-split). One LDS tile tT,
// ping-ponged: gather->tT, G1 reads tT / epil1 writes tT, G2 reads / epil2 writes,
// G3 reads -> out. Barrier between each read-phase and write-phase.
__global__ __launch_bounds__(256) void k_fused(const unsigned short* __restrict__ fT,
                                               const float* __restrict__ verts,
                                               const int* __restrict__ iszp,
                                               const unsigned short* __restrict__ WT,
                                               const float* __restrict__ b1,
                                               const float* __restrict__ b2,
                                               const float* __restrict__ bpv,
                                               float* __restrict__ out, int b0) {
    __shared__ __align__(16) unsigned short tT[64][264];  // pitch 528B = 16*33 (odd quad)
    __shared__ __align__(16) int pIdx[64][4];
    __shared__ __align__(16) float wBl[64][4];
    __shared__ float vps[64][2];
    __shared__ __align__(16) float b1s[256];
    __shared__ float b2s[256], bps[256];

    const unsigned short* W1T = WT;
    const unsigned short* W2T = WT + 65536;
    const unsigned short* WpT = WT + 131072;

    const int blk = blockIdx.x;
    const int bl = blk >> 6;
    const int b = b0 + bl;
    const int n0 = (blk & 63) << 6;
    const int t = threadIdx.x;
    const int lane = t & 63;
    const int w = t >> 6;

    b1s[t] = b1[t];
    b2s[t] = b2[t];
    bps[t] = bpv[t];

    if (t < 64) {
        const float isz = (float)iszp[0];
        const size_t vo = ((size_t)b * Nn + n0 + t) << 1;
        const float vx = verts[vo + 0];
        const float vy = verts[vo + 1];
        const float gs = 127.0f / (isz - 1.0f);
        const float ix = fminf(fmaxf(vx * gs, 0.0f), 127.0f);
        const float iy = fminf(fmaxf(vy * gs, 0.0f), 127.0f);
        const float x0 = floorf(ix), y0 = floorf(iy);
        const float wx = ix - x0, wy = iy - y0;
        const int x0i = (int)x0, y0i = (int)y0;
        const int x1i = min(x0i + 1, 127), y1i = min(y0i + 1, 127);
        pIdx[t][0] = (y0i << 7) + x0i;
        pIdx[t][1] = (y0i << 7) + x1i;
        pIdx[t][2] = (y1i << 7) + x0i;
        pIdx[t][3] = (y1i << 7) + x1i;
        wBl[t][0] = (1.0f - wx) * (1.0f - wy);
        wBl[t][1] = wx * (1.0f - wy);
        wBl[t][2] = (1.0f - wx) * wy;
        wBl[t][3] = wx * wy;
        vps[t][0] = vx / isz;
        vps[t][1] = vy / isz;
    }
    __syncthreads();

    // ---- gather (coalesced 512B bf16 rows of fT) + bilinear blend -> tT (bf16) ----
    {
        const unsigned short* Fb = fT + ((size_t)bl << 22);
        for (int i = 0; i < 16; ++i) {
            const int r = (w << 4) + i;
            const int4 pp = *(const int4*)pIdx[r];
            const float4 wt = *(const float4*)wBl[r];
            const uint2 a0 = *(const uint2*)(Fb + ((size_t)pp.x << 8) + (lane << 2));
            const uint2 a1 = *(const uint2*)(Fb + ((size_t)pp.y << 8) + (lane << 2));
            const uint2 a2 = *(const uint2*)(Fb + ((size_t)pp.z << 8) + (lane << 2));
            const uint2 a3 = *(const uint2*)(Fb + ((size_t)pp.w << 8) + (lane << 2));
            const float d0 = wt.x * bf2f(a0.x & 0xffffu) + wt.y * bf2f(a1.x & 0xffffu) +
                             wt.z * bf2f(a2.x & 0xffffu) + wt.w * bf2f(a3.x & 0xffffu);
            const float d1 = wt.x * bf2f(a0.x >> 16) + wt.y * bf2f(a1.x >> 16) +
                             wt.z * bf2f(a2.x >> 16) + wt.w * bf2f(a3.x >> 16);
            const float d2 = wt.x * bf2f(a0.y & 0xffffu) + wt.y * bf2f(a1.y & 0xffffu) +
                             wt.z * bf2f(a2.y & 0xffffu) + wt.w * bf2f(a3.y & 0xffffu);
            const float d3 = wt.x * bf2f(a0.y >> 16) + wt.y * bf2f(a1.y >> 16) +
                             wt.z * bf2f(a2.y >> 16) + wt.w * bf2f(a3.y >> 16);
            uint2 pk;
            pk.x = pack2(f2bf(d0), f2bf(d1));
            pk.y = pack2(f2bf(d2), f2bf(d3));
            *(uint2*)&tT[r][lane << 2] = pk;
        }
    }
    __syncthreads();

    const int mrow = lane & 15;
    const int kg = (lane >> 4) << 3;
    const int r0 = (lane >> 4) << 2;
    const int n0w = w << 6;

    f32x4 acc[4][4];
    us8t bnx[4];

    // ---- GEMM1: h = sampled @ W1 ----
#pragma unroll
    for (int i = 0; i < 4; ++i)
#pragma unroll
        for (int j = 0; j < 4; ++j) acc[i][j] = (f32x4){0.f, 0.f, 0.f, 0.f};
#pragma unroll
    for (int nt = 0; nt < 4; ++nt)
        bnx[nt] = *(const us8t*)(W1T + ((n0w + (nt << 4) + mrow) << 8) + kg);
    for (int k0 = 0; k0 < 256; k0 += 32) {
        us8t bcur[4];
#pragma unroll
        for (int nt = 0; nt < 4; ++nt) bcur[nt] = bnx[nt];
        if (k0 < 224) {
#pragma unroll
            for (int nt = 0; nt < 4; ++nt)
                bnx[nt] = *(const us8t*)(W1T + ((n0w + (nt << 4) + mrow) << 8) + k0 + 32 + kg);
        }
        us8t af[4];
#pragma unroll
        for (int mt = 0; mt < 4; ++mt)
            af[mt] = *(const us8t*)&tT[(mt << 4) + mrow][k0 + kg];
#pragma unroll
        for (int mt = 0; mt < 4; ++mt)
#pragma unroll
            for (int nt = 0; nt < 4; ++nt)
                acc[mt][nt] = mfma16(af[mt], bcur[nt], acc[mt][nt]);
    }
    __syncthreads();  // all tT reads done

    // ---- epilogue 1: tT = bf16(relu(h + b1)) ----
#pragma unroll
    for (int nt = 0; nt < 4; ++nt) {
        const int col = n0w + (nt << 4) + mrow;
        const float bb1 = b1s[col];
#pragma unroll
        for (int mt = 0; mt < 4; ++mt)
#pragma unroll
            for (int j = 0; j < 4; ++j) {
                const int row = (mt << 4) + r0 + j;
                tT[row][col] = f2bf(fmaxf(acc[mt][nt][j] + bb1, 0.0f));
            }
    }
    __syncthreads();

    // ---- GEMM2: vfeat = h @ W2 ----
#pragma unroll
    for (int i = 0; i < 4; ++i)
#pragma unroll
        for (int j = 0; j < 4; ++j) acc[i][j] = (f32x4){0.f, 0.f, 0.f, 0.f};
#pragma unroll
    for (int nt = 0; nt < 4; ++nt)
        bnx[nt] = *(const us8t*)(W2T + ((n0w + (nt << 4) + mrow) << 8) + kg);
    for (int k0 = 0; k0 < 256; k0 += 32) {
        us8t bcur[4];
#pragma unroll
        for (int nt = 0; nt < 4; ++nt) bcur[nt] = bnx[nt];
        if (k0 < 224) {
#pragma unroll
            for (int nt = 0; nt < 4; ++nt)
                bnx[nt] = *(const us8t*)(W2T + ((n0w + (nt << 4) + mrow) << 8) + k0 + 32 + kg);
        }
        us8t af[4];
#pragma unroll
        for (int mt = 0; mt < 4; ++mt)
            af[mt] = *(const us8t*)&tT[(mt << 4) + mrow][k0 + kg];
#pragma unroll
        for (int mt = 0; mt < 4; ++mt)
#pragma unroll
            for (int nt = 0; nt < 4; ++nt)
                acc[mt][nt] = mfma16(af[mt], bcur[nt], acc[mt][nt]);
    }
    __syncthreads();  // all tT reads done

    // ---- epilogue 2: tT = bf16(vfeat + b2 + posenc) ----
    const float C2 = -0.20762050593046f;  // -log2(10000)/64
#pragma unroll
    for (int nt = 0; nt < 4; ++nt) {
        const int col = n0w + (nt << 4) + mrow;
        const float bias2 = b2s[col];
        const int ci = col & 127;
        const float dv = exp2f((float)(ci >> 1) * C2) * 1000.0f;
        const int sel = col >> 7;  // 0 -> x, 1 -> y
#pragma unroll
        for (int mt = 0; mt < 4; ++mt)
#pragma unroll
            for (int j = 0; j < 4; ++j) {
                const int row = (mt << 4) + r0 + j;
                const float ang = vps[row][sel] * dv;
                const float pe = (col & 1) ? __cosf(ang) : __sinf(ang);
                tT[row][col] = f2bf(acc[mt][nt][j] + bias2 + pe);
            }
    }
    __syncthreads();

    // ---- GEMM3: out = g @ Wp + bp ----
#pragma unroll
    for (int i = 0; i < 4; ++i)
#pragma unroll
        for (int j = 0; j < 4; ++j) acc[i][j] = (f32x4){0.f, 0.f, 0.f, 0.f};
#pragma unroll
    for (int nt = 0; nt < 4; ++nt)
        bnx[nt] = *(const us8t*)(WpT + ((n0w + (nt << 4) + mrow) << 8) + kg);
    for (int k0 = 0; k0 < 256; k0 += 32) {
        us8t bcur[4];
#pragma unroll
        for (int nt = 0; nt < 4; ++nt) bcur[nt] = bnx[nt];
        if (k0 < 224) {
#pragma unroll
            for (int nt = 0; nt < 4; ++nt)
                bnx[nt] = *(const us8t*)(WpT + ((n0w + (nt << 4) + mrow) << 8) + k0 + 32 + kg);
        }
        us8t af[4];
#pragma unroll
        for (int mt = 0; mt < 4; ++mt)
            af[mt] = *(const us8t*)&tT[(mt << 4) + mrow][k0 + kg];
#pragma unroll
        for (int mt = 0; mt < 4; ++mt)
#pragma unroll
            for (int nt = 0; nt < 4; ++nt)
                acc[mt][nt] = mfma16(af[mt], bcur[nt], acc[mt][nt]);
    }

    float* ob = out + (((size_t)b * Nn + n0) << 8);
#pragma unroll
    for (int nt = 0; nt < 4; ++nt) {
        const int col = n0w + (nt << 4) + mrow;
        const float bb = bps[col];
#pragma unroll
        for (int mt = 0; mt < 4; ++mt)
#pragma unroll
            for (int j = 0; j < 4; ++j) {
                const int row = (mt << 4) + r0 + j;
                ob[((size_t)row << 8) + col] = acc[mt][nt][j] + bb;
            }
    }
}

extern "C" void kernel_launch(void* const* d_in, const int* in_sizes, int n_in,
                              void* d_out, int out_size, void* d_ws, size_t ws_size,
                              hipStream_t stream) {
    const float* f = (const float*)d_in[0];
    const float* verts = (const float*)d_in[1];
    const int* isz = (const int*)d_in[2];
    const float* W1 = (const float*)d_in[3];
    const float* b1 = (const float*)d_in[4];
    const float* W2 = (const float*)d_in[5];
    const float* b2 = (const float*)d_in[6];
    const float* Wp = (const float*)d_in[7];
    const float* bp = (const float*)d_in[8];
    float* out = (float*)d_out;

    unsigned short* WT = (unsigned short*)d_ws;                       // 3 x 128KB bf16 transposed
    const size_t S_OFF = 512u << 10;
    unsigned short* fT = (unsigned short*)((char*)d_ws + S_OFF);

    const size_t perBatch = (size_t)HW * 256 * 2;  // 8 MB bf16 per batch
    size_t sbytes = (ws_size > S_OFF) ? (ws_size - S_OFF) : 0;
    int nbMax = (int)(sbytes / perBatch);
    if (nbMax < 1) nbMax = 1;
    if (nbMax > 16) nbMax = 16;

    k_wt<<<dim3(768), dim3(256), 0, stream>>>(W1, W2, Wp, WT);
    for (int b0 = 0; b0 < 16; b0 += nbMax) {
        const int nb = (16 - b0 < nbMax) ? (16 - b0) : nbMax;
        k_tr<<<dim3(nb * 256), dim3(256), 0, stream>>>(f, fT, b0);
        k_fused<<<dim3(nb * 64), dim3(256), 0, stream>>>(fT, verts, isz, WT,
                                                         b1, b2, bp, out, b0);
    }
}